// Round 2
// baseline (16.291 us; speedup 1.0000x reference)
//
#include <hip/hip_runtime.h>
#include <hip/hip_bf16.h>

// Problem constants (from reference setup_inputs)
#define XW   65536   // W
#define XC   256     // C
#define XL   512     // LATENT_DIM (output bins)
#define BIN  128     // W / L elements per bin

// One block per output bin l. 1024 threads = 32 c-groups (8 channels each)
// x 32 lanes (4 w's each via float4). Only batch 0 of x is read (the output
// depends only on batch 0). Full occupancy: 512 blocks x 16 waves = 2 blocks/CU
// = 32 waves/CU.
__global__ __launch_bounds__(1024) void statspool_kernel(
    const float* __restrict__ x,     // [B,C,1,W] -- we read only b=0
    const float* __restrict__ cw,    // [1,C]
    const float* __restrict__ cb,    // [1]
    const float* __restrict__ eps,   // [L]
    float* __restrict__ out)         // [1,L]
{
    const int l  = blockIdx.x;       // bin index 0..511
    const int t  = threadIdx.x;      // 0..1023
    const int wi = t & 31;           // lane-in-group -> 4 consecutive w's
    const int cg = t >> 5;           // c-group 0..31 (8 channels each)

    // weights for this thread's 8 channels -> registers
    const float4 wA = *(const float4*)(cw + (cg << 3));
    const float4 wB = *(const float4*)(cw + (cg << 3) + 4);
    const float wgt[8] = {wA.x, wA.y, wA.z, wA.w, wB.x, wB.y, wB.z, wB.w};

    const float* xp = x + (size_t)(cg << 3) * XW + l * BIN + (wi << 2);

    float4 acc = make_float4(0.f, 0.f, 0.f, 0.f);
    #pragma unroll
    for (int c = 0; c < 8; ++c) {
        const float4 v = *(const float4*)(xp + (size_t)c * XW);
        acc.x = fmaf(wgt[c], v.x, acc.x);
        acc.y = fmaf(wgt[c], v.y, acc.y);
        acc.z = fmaf(wgt[c], v.z, acc.z);
        acc.w = fmaf(wgt[c], v.w, acc.w);
    }

    // Stage partials: part[cg][w] flat, w = wi*4 + k. Contiguous b128 writes.
    __shared__ float part[32 * BIN];     // 16 KB
    __shared__ float ob[BIN];            // o values for this bin
    *(float4*)(part + (cg << 7) + (wi << 2)) = acc;
    __syncthreads();

    // 128 threads each own one w: sum the 32 c-group partials (stride-1 reads,
    // conflict-free), add bias.
    if (t < BIN) {
        float s = 0.f;
        #pragma unroll
        for (int g = 0; g < 32; ++g) s += part[(g << 7) + t];
        ob[t] = s + cb[0];
    }
    __syncthreads();

    // One wave reduces sum / sum-of-squares over the 128 o's.
    if (t < 64) {
        const float o0 = ob[t];
        const float o1 = ob[t + 64];
        float s  = o0 + o1;
        float sq = fmaf(o0, o0, o1 * o1);
        #pragma unroll
        for (int off = 32; off; off >>= 1) {
            s  += __shfl_down(s,  off);
            sq += __shfl_down(sq, off);
        }
        if (t == 0) {
            const float inv  = 1.0f / (float)BIN;
            const float mean = s * inv;
            const float msq  = sq * inv;
            const float var  = fmaxf(msq - mean * mean, 0.0f);
            out[l] = fmaf(sqrtf(var), eps[l], mean);
        }
    }
}

extern "C" void kernel_launch(void* const* d_in, const int* in_sizes, int n_in,
                              void* d_out, int out_size, void* d_ws, size_t ws_size,
                              hipStream_t stream) {
    const float* x   = (const float*)d_in[0];   // [8,256,1,65536] f32
    const float* cw  = (const float*)d_in[1];   // [1,256] f32
    const float* cb  = (const float*)d_in[2];   // [1] f32
    const float* eps = (const float*)d_in[3];   // [512] f32
    float* out = (float*)d_out;                 // [1,512] f32

    statspool_kernel<<<dim3(XL), dim3(1024), 0, stream>>>(x, cw, cb, eps, out);
}